// Round 1
// baseline (760.488 us; speedup 1.0000x reference)
//
#include <hip/hip_runtime.h>

// KW_CascadedBranch: audio->CLIP keyword VQ.
//   kw = audio @ W + b; kw_n = normalize(kw)
//   s[b,n,v] = (kw_n . emb_v) * (10 / max(||emb_v||, 1e-8))   (cos/TEMP folded)
//   out = (sum_v exp(s) * emb_v) / sum_v exp(s)               (no max-sub needed: |s|<=~10.5)
//
// K1 prep_emb : emb f32 -> bf16 copy + per-row scale = 10/max(norm,eps)
// K2 proj_kw  : kw = audio@W+b (f32 vector), normalize, write bf16 kw_n
// K3 attn     : fused flash-style QK^T -> exp -> PV, MFMA bf16, split-vocab partials
// K4 combine  : out = sum_vs O_part / sum_vs l_part

typedef __attribute__((ext_vector_type(8))) short short8;   // 8 x bf16 (4 VGPR)
typedef __attribute__((ext_vector_type(4))) float f32x4;    // MFMA 16x16x32 acc

#define B_   256
#define N_   8
#define DM   768
#define TD   512
#define V_   49408
#define M_   (B_*N_)        // 2048 query rows
#define QB   64             // q rows per attn block
#define NQB  (M_/QB)        // 32
#define VS   8              // vocab splits
#define SPLIT (V_/VS)       // 6176
#define VT   64             // vocab tile
#define NT   97             // 96 full tiles + tail of 32

__device__ inline unsigned short f2bf(float x){   // RNE f32 -> bf16 (no NaN inputs here)
  unsigned u = __builtin_bit_cast(unsigned, x);
  u += 0x7fffu + ((u>>16)&1u);
  return (unsigned short)(u>>16);
}

// ---------------- K1: emb -> bf16 + scale ----------------
__global__ __launch_bounds__(256) void prep_emb(const float* __restrict__ emb,
                                                unsigned short* __restrict__ embB,
                                                float* __restrict__ scale){
  int v = blockIdx.x*4 + (threadIdx.x>>6);   // one wave per vocab row
  int l = threadIdx.x&63;
  const float4* row = (const float4*)(emb + (size_t)v*TD);
  float4 x0 = row[2*l], x1 = row[2*l+1];
  float s = x0.x*x0.x+x0.y*x0.y+x0.z*x0.z+x0.w*x0.w
          + x1.x*x1.x+x1.y*x1.y+x1.z*x1.z+x1.w*x1.w;
  #pragma unroll
  for (int m=1;m<64;m<<=1) s += __shfl_xor(s, m, 64);
  float sc = 10.0f / fmaxf(sqrtf(s), 1e-8f);   // 1/TEMP folded in
  uint4 o;
  o.x = f2bf(x0.x) | ((unsigned)f2bf(x0.y)<<16);
  o.y = f2bf(x0.z) | ((unsigned)f2bf(x0.w)<<16);
  o.z = f2bf(x1.x) | ((unsigned)f2bf(x1.y)<<16);
  o.w = f2bf(x1.z) | ((unsigned)f2bf(x1.w)<<16);
  *((uint4*)(embB + (size_t)v*TD) + l) = o;
  if (l==0) scale[v] = sc;
}

// ---------------- K2: kw = audio@W+b, normalize, bf16 ----------------
__global__ __launch_bounds__(512) void proj_kw(const float* __restrict__ audio,
                                               const float* __restrict__ W,
                                               const float* __restrict__ bias,
                                               unsigned short* __restrict__ kwn){
  __shared__ float a[16][772];      // 16 audio rows, padded (reads are uniform-broadcast)
  __shared__ float kwt[16][TD];
  int tid = threadIdx.x;
  int row0 = blockIdx.x*16;
  #pragma unroll
  for (int j=0;j<6;j++){
    int idx = tid + 512*j;          // 3072 float4 = 16 rows x 192
    int r = idx/192, c4 = idx%192;
    *(float4*)&a[r][4*c4] = ((const float4*)(audio + (size_t)(row0+r)*DM))[c4];
  }
  __syncthreads();
  int c = tid;                      // one output column per thread
  float acc[16];
  #pragma unroll
  for (int r=0;r<16;r++) acc[r]=0.f;
  float wrA[4], wrB[4];
  #pragma unroll
  for (int kk=0;kk<4;kk++) wrA[kk] = W[(size_t)kk*TD + c];
  for (int k4=0;k4<192;k4+=2){      // manual 2x unroll, named prefetch regs (no dyn idx)
    #pragma unroll
    for (int kk=0;kk<4;kk++) wrB[kk] = W[(size_t)(4*k4+4+kk)*TD + c];
    #pragma unroll
    for (int r=0;r<16;r++){
      float4 av = *(const float4*)&a[r][4*k4];
      acc[r] += av.x*wrA[0] + av.y*wrA[1] + av.z*wrA[2] + av.w*wrA[3];
    }
    #pragma unroll
    for (int kk=0;kk<4;kk++){ int k = 4*k4+8+kk; if (k>767) k=767; wrA[kk] = W[(size_t)k*TD + c]; }
    #pragma unroll
    for (int r=0;r<16;r++){
      float4 av = *(const float4*)&a[r][4*k4+4];
      acc[r] += av.x*wrB[0] + av.y*wrB[1] + av.z*wrB[2] + av.w*wrB[3];
    }
  }
  float bb = bias[c];
  #pragma unroll
  for (int r=0;r<16;r++) kwt[r][c] = acc[r] + bb;
  __syncthreads();
  int w = tid>>6, l = tid&63;
  #pragma unroll
  for (int rr=0;rr<2;rr++){
    int r = 2*w+rr;
    float4 x0 = *(const float4*)&kwt[r][8*l];
    float4 x1 = *(const float4*)&kwt[r][8*l+4];
    float s = x0.x*x0.x+x0.y*x0.y+x0.z*x0.z+x0.w*x0.w
            + x1.x*x1.x+x1.y*x1.y+x1.z*x1.z+x1.w*x1.w;
    #pragma unroll
    for (int m=1;m<64;m<<=1) s += __shfl_xor(s, m, 64);
    float sc = 1.0f/fmaxf(sqrtf(s), 1e-8f);
    uint4 o;
    o.x = f2bf(x0.x*sc) | ((unsigned)f2bf(x0.y*sc)<<16);
    o.y = f2bf(x0.z*sc) | ((unsigned)f2bf(x0.w*sc)<<16);
    o.z = f2bf(x1.x*sc) | ((unsigned)f2bf(x1.y*sc)<<16);
    o.w = f2bf(x1.z*sc) | ((unsigned)f2bf(x1.w*sc)<<16);
    *((uint4*)(kwn + (size_t)(row0+r)*TD) + l) = o;
  }
}

// ---------------- K3: fused attention over vocab ----------------
// grid = 32 qblocks x 8 vsplits; 512 thr (8 waves).
// wave w: S-phase computes q-tile (w>>1), v-tile-pair (w&1); PV owns d-cols [64w,64w+64).
__global__ __launch_bounds__(512,2) void attn(const unsigned short* __restrict__ embB,
                                              const float* __restrict__ scale,
                                              const unsigned short* __restrict__ kwn,
                                              float* __restrict__ Opart,
                                              float* __restrict__ lpart){
  __shared__ unsigned short embK[64][520];  // +8 pad: stride 1040B -> 2-way-free b128 reads
  __shared__ unsigned short P[64][72];      // exp(score) bf16; stride 144B
  __shared__ float l_lds[64];
  int tid = threadIdx.x;
  int w = tid>>6;
  int l = tid&63;
  int c = l&15, g = l>>4;
  int qb = blockIdx.x>>3, vs = blockIdx.x&7;
  int qr = w>>1, vp = w&1;
  if (tid<64) l_lds[tid]=0.f;

  // hoist Q fragments: rows qb*64 + qr*16 + c, all 16 k-steps (64 VGPR)
  short8 qf[16];
  {
    const short8* qp = (const short8*)(kwn + (size_t)(qb*QB + qr*16 + c)*TD);
    #pragma unroll
    for (int ks=0;ks<16;ks++) qf[ks] = qp[4*ks+g];
  }
  f32x4 acc[4][4];
  #pragma unroll
  for (int i=0;i<4;i++){
    #pragma unroll
    for (int j=0;j<4;j++) acc[i][j] = (f32x4){0.f,0.f,0.f,0.f};
  }

  int vbase0 = vs*SPLIT;
  for (int t=0;t<NT;t++){
    int vb = vbase0 + t*VT;
    int vcnt = SPLIT - t*VT; if (vcnt>VT) vcnt=VT;   // 64 except tail=32
    __syncthreads();                                  // prev PV done before restage
    #pragma unroll
    for (int i=0;i<8;i++){                            // stage 64x512 bf16 (1KB/row/wave-instr)
      int vr = 8*i + w;
      uint4 val;
      if (vr < vcnt) val = *((const uint4*)(embB + (size_t)(vb+vr)*TD) + l);
      else           val = make_uint4(0,0,0,0);       // zero-pad tail rows
      *(uint4*)&embK[vr][8*l] = val;
    }
    __syncthreads();
    // ---- S = Q . emb^T (per wave: 2 16x16 tiles, 16 k-steps) ----
    f32x4 s0 = (f32x4){0.f,0.f,0.f,0.f};
    f32x4 s1 = (f32x4){0.f,0.f,0.f,0.f};
    #pragma unroll
    for (int ks=0;ks<16;ks++){
      short8 b0 = *(const short8*)&embK[32*vp + c][32*ks + 8*g];
      short8 b1 = *(const short8*)&embK[32*vp + 16 + c][32*ks + 8*g];
      s0 = __builtin_amdgcn_mfma_f32_16x16x32_bf16(qf[ks], b0, s0, 0,0,0);
      s1 = __builtin_amdgcn_mfma_f32_16x16x32_bf16(qf[ks], b1, s1, 0,0,0);
    }
    // ---- scale, exp, mask tail, write P (bf16), accumulate l ----
    int lv0 = 32*vp + c, lv1 = 32*vp + 16 + c;
    int gv0 = vb + lv0; if (gv0 > V_-1) gv0 = V_-1;
    int gv1 = vb + lv1; if (gv1 > V_-1) gv1 = V_-1;
    float sc0 = scale[gv0], sc1 = scale[gv1];
    float ls[4];
    #pragma unroll
    for (int j=0;j<4;j++){
      float p0 = (lv0 < vcnt) ? __expf(s0[j]*sc0) : 0.f;
      float p1 = (lv1 < vcnt) ? __expf(s1[j]*sc1) : 0.f;
      P[16*qr + 4*g + j][lv0] = f2bf(p0);
      P[16*qr + 4*g + j][lv1] = f2bf(p1);
      ls[j] = p0+p1;
    }
    #pragma unroll
    for (int m=1;m<16;m<<=1){
      #pragma unroll
      for (int j=0;j<4;j++) ls[j] += __shfl_xor(ls[j], m, 64);
    }
    if (c==0){
      #pragma unroll
      for (int j=0;j<4;j++) atomicAdd(&l_lds[16*qr + 4*g + j], ls[j]);
    }
    __syncthreads();                                  // P ready
    // ---- O += P . emb (wave owns d-cols 64w..64w+63) ----
    #pragma unroll
    for (int ks=0;ks<2;ks++){
      short8 af[4];
      #pragma unroll
      for (int qt=0;qt<4;qt++) af[qt] = *(const short8*)&P[16*qt + c][32*ks + 8*g];
      #pragma unroll
      for (int dt=0;dt<4;dt++){
        short8 bv;                                    // strided u16 gather (fix in later round)
        #pragma unroll
        for (int e=0;e<8;e++) bv[e] = (short)embK[32*ks + 8*g + e][64*w + 16*dt + c];
        #pragma unroll
        for (int qt=0;qt<4;qt++)
          acc[qt][dt] = __builtin_amdgcn_mfma_f32_16x16x32_bf16(af[qt], bv, acc[qt][dt], 0,0,0);
      }
    }
  }
  __syncthreads();
  float* op = Opart + (size_t)(qb*VS + vs)*QB*TD;
  #pragma unroll
  for (int qt=0;qt<4;qt++){
    #pragma unroll
    for (int dt=0;dt<4;dt++){
      #pragma unroll
      for (int j=0;j<4;j++)
        op[(size_t)(16*qt + 4*g + j)*TD + 64*w + 16*dt + c] = acc[qt][dt][j];
    }
  }
  if (tid<64) lpart[(size_t)(qb*VS+vs)*QB + tid] = l_lds[tid];
}

// ---------------- K4: combine split-vocab partials ----------------
__global__ __launch_bounds__(256) void combine(const float* __restrict__ Opart,
                                               const float* __restrict__ lpart,
                                               float* __restrict__ out){
  int m = blockIdx.x;
  int qb = m>>6, r = m&63;
  int t = threadIdx.x;
  float ls = 0.f;
  #pragma unroll
  for (int v=0;v<VS;v++) ls += lpart[(size_t)(qb*VS+v)*QB + r];
  float inv = 1.0f/ls;
  for (int cc=t; cc<TD; cc+=256){
    float s = 0.f;
    #pragma unroll
    for (int v=0;v<VS;v++) s += Opart[((size_t)(qb*VS+v)*QB + r)*TD + cc];
    out[(size_t)m*TD + cc] = s*inv;
  }
}

extern "C" void kernel_launch(void* const* d_in, const int* in_sizes, int n_in,
                              void* d_out, int out_size, void* d_ws, size_t ws_size,
                              hipStream_t stream){
  const float* audio = (const float*)d_in[0];   // [256,8,768]
  const float* W     = (const float*)d_in[1];   // [768,512]
  const float* bias  = (const float*)d_in[2];   // [512]
  const float* emb   = (const float*)d_in[3];   // [49408,512]
  float* out = (float*)d_out;                   // [2048,512] f32
  char* ws = (char*)d_ws;
  // ws layout (total 86,508,544 B)
  unsigned short* embB  = (unsigned short*)(ws);             // 50,593,792
  float*          scale = (float*)(ws + 50593792);           //    197,632
  unsigned short* kwn   = (unsigned short*)(ws + 50791424);  //  2,097,152
  float*          Opart = (float*)(ws + 52888576);           // 33,554,432
  float*          lpart = (float*)(ws + 86443008);           //     65,536

  hipLaunchKernelGGL(prep_emb, dim3(V_/4),   dim3(256), 0, stream, emb, embB, scale);
  hipLaunchKernelGGL(proj_kw,  dim3(M_/16),  dim3(512), 0, stream, audio, W, bias, kwn);
  hipLaunchKernelGGL(attn,     dim3(NQB*VS), dim3(512), 0, stream, embB, scale, kwn, Opart, lpart);
  hipLaunchKernelGGL(combine,  dim3(M_),     dim3(256), 0, stream, Opart, lpart, out);
}